// Round 18
// baseline (68.487 us; speedup 1.0000x reference)
//
#include <hip/hip_runtime.h>

#define IMG   512
#define NCLS  256
#define DIM   1024
#define HPW   32
#define TPB   16           // tokens per block = full MFMA M
#define NT    1024         // 16 waves; wave owns 64 dims
#define MAGIC 0x5EEDC0DEu
#define REPS  3            // DIAGNOSTIC: triplicate body for rocprof visibility

typedef short bf16x8 __attribute__((ext_vector_type(8)));
typedef float f32x4  __attribute__((ext_vector_type(4)));

__device__ inline ushort bf16rne(float v) {
    unsigned u = __float_as_uint(v);
    return (ushort)((u + 0x7fffu + ((u >> 16) & 1u)) >> 16);
}

// DIAGNOSTIC build of R16's single-launch kernel: identical phases, whole body
// repeated REPS times (reps >=1 rewrite identical data; benign by construction).
__global__ __launch_bounds__(NT)
void fused_one(const int* __restrict__ smap, const float* __restrict__ table,
               const float* __restrict__ gamma, const float* __restrict__ beta,
               float* __restrict__ out, ushort* __restrict__ Tt2,
               unsigned* __restrict__ flags)
{
    __shared__ unsigned cnt[TPB * NCLS];      // 16 KB
    __shared__ ushort   pk[2048];             // 4 KB pack staging
    __shared__ ushort   cntb[16][264];        // stride 528 B -> conflict-free b128
    __shared__ float    red[16][4][4][2];     // [wave][g][i][{s,s2}]

    const int t    = threadIdx.x;
    const int lane = t & 63;
    const int w    = t >> 6;
    const int c    = lane & 15;
    const int g    = lane >> 4;

    const int bid  = blockIdx.x;
    const int tok0 = bid * TPB;
    const int b    = tok0 >> 10;
    const int ph   = (tok0 >> 5) & 31;
    const int pw0  = tok0 & 31;

    const int dtile = bid >> 1;
    const int kh    = bid & 1;

    for (int rep = 0; rep < REPS; ++rep) {

    // ---- 1) pack-load: 128 cls x 16 dims -> LDS scatter (fragment order) ----
    if (t < 512) {
        const int cls  = kh * 128 + (t >> 2);
        const int quad = t & 3;
        const float4 v = *reinterpret_cast<const float4*>(
            table + (size_t)cls * DIM + dtile * 16 + quad * 4);
        const int ks = cls >> 5, gg = (cls >> 3) & 3, j = cls & 7;
        ushort* dst = pk + (ks & 3) * 512 + gg * 128 + j;
        dst[(quad * 4 + 0) * 8] = bf16rne(v.x);
        dst[(quad * 4 + 1) * 8] = bf16rne(v.y);
        dst[(quad * 4 + 2) * 8] = bf16rne(v.z);
        dst[(quad * 4 + 3) * 8] = bf16rne(v.w);
    }
    // ---- 2) zero hist ----
    for (int i = t; i < TPB * NCLS; i += NT) cnt[i] = 0u;
    __syncthreads();

    // ---- 3) pack copy-out: system-scope atomic dwords ----
    {
        const unsigned val = (unsigned)pk[t * 2] | ((unsigned)pk[t * 2 + 1] << 16);
        __hip_atomic_store((unsigned*)Tt2 + (size_t)dtile * 2048 + kh * 1024 + t, val,
                           __ATOMIC_RELAXED, __HIP_MEMORY_SCOPE_SYSTEM);
    }
    __syncthreads();

    // ---- 4) publish pack completion ----
    if (t == 0)
        __hip_atomic_store(&flags[bid], MAGIC, __ATOMIC_RELEASE, __HIP_MEMORY_SCOPE_SYSTEM);

    // ---- 5) histogram ----
    {
        const int row = t >> 6;
        const int col = (t & 63) * 4;
        const int4 q = *reinterpret_cast<const int4*>(
            smap + ((size_t)b * IMG + (size_t)(ph * 16 + row)) * IMG + pw0 * 16 + col);
        unsigned* hp = &cnt[(col >> 4) * NCLS];
        atomicAdd(&hp[min(max(q.x, 0), NCLS - 1)], 1u);
        atomicAdd(&hp[min(max(q.y, 0), NCLS - 1)], 1u);
        atomicAdd(&hp[min(max(q.z, 0), NCLS - 1)], 1u);
        atomicAdd(&hp[min(max(q.w, 0), NCLS - 1)], 1u);
    }
    __syncthreads();

    // ---- 6) counts -> bf16(count/256) ----
    for (int i = t; i < TPB * NCLS; i += NT)
        cntb[i >> 8][i & 255] = (ushort)(__float_as_uint((float)cnt[i] * (1.f / 256.f)) >> 16);

    // ---- 7) wait for all packers ----
    if (t < 128) {
        while (__hip_atomic_load(&flags[t], __ATOMIC_ACQUIRE,
                                 __HIP_MEMORY_SCOPE_SYSTEM) != MAGIC) {}
    }
    __syncthreads();

    // ---- 8) MFMA K-loop ----
    f32x4 acc[4];
    #pragma unroll
    for (int i = 0; i < 4; ++i) acc[i] = (f32x4){0.f, 0.f, 0.f, 0.f};

    const ushort* bt = Tt2 + (size_t)(w * 4) * 4096 + (size_t)lane * 8;
    #pragma unroll 2
    for (int ks = 0; ks < 8; ++ks) {
        const bf16x8 a = *reinterpret_cast<const bf16x8*>(&cntb[c][ks * 32 + g * 8]);
        bf16x8 bfv[4];
        #pragma unroll
        for (int nf = 0; nf < 4; ++nf)
            bfv[nf] = *reinterpret_cast<const bf16x8*>(bt + (size_t)nf * 4096 + ks * 512);
        #pragma unroll
        for (int nf = 0; nf < 4; ++nf)
            acc[nf] = __builtin_amdgcn_mfma_f32_16x16x32_bf16(a, bfv[nf], acc[nf], 0, 0, 0);
    }

    // ---- 9) pos-embed + LN partials ----
    const int quad   = w >> 2;
    const int cosSel = quad & 1;
    float ls[4]  = {0, 0, 0, 0};
    float ls2[4] = {0, 0, 0, 0};

    #pragma unroll
    for (int nf = 0; nf < 4; ++nf) {
        const int dlow = (w & 3) * 64 + nf * 16 + c;
        const float omega = exp2f((float)dlow * (-13.287712379549449f / 256.f));
        if (quad < 2) {
            float sv, cv; __sincosf((float)ph * omega, &sv, &cv);
            const float v = cosSel ? cv : sv;
            #pragma unroll
            for (int i = 0; i < 4; ++i) acc[nf][i] += v;
        } else {
            #pragma unroll
            for (int i = 0; i < 4; ++i) {
                float sv, cv; __sincosf((float)(pw0 + g * 4 + i) * omega, &sv, &cv);
                acc[nf][i] += cosSel ? cv : sv;
            }
        }
        #pragma unroll
        for (int i = 0; i < 4; ++i) { ls[i] += acc[nf][i]; ls2[i] += acc[nf][i] * acc[nf][i]; }
    }

    #pragma unroll
    for (int off = 1; off < 16; off <<= 1) {
        #pragma unroll
        for (int i = 0; i < 4; ++i) {
            ls[i]  += __shfl_xor(ls[i],  off, 64);
            ls2[i] += __shfl_xor(ls2[i], off, 64);
        }
    }
    if (c == 0) {
        #pragma unroll
        for (int i = 0; i < 4; ++i) { red[w][g][i][0] = ls[i]; red[w][g][i][1] = ls2[i]; }
    }
    __syncthreads();

    // ---- 10) finalize LN + store ----
    {
        float mu[4], rs[4];
        #pragma unroll
        for (int i = 0; i < 4; ++i) {
            float S = 0.f, S2 = 0.f;
            #pragma unroll
            for (int ww = 0; ww < 16; ++ww) { S += red[ww][g][i][0]; S2 += red[ww][g][i][1]; }
            mu[i] = S * (1.f / DIM);
            rs[i] = rsqrtf(S2 * (1.f / DIM) - mu[i] * mu[i] + 1e-5f);
        }
        #pragma unroll
        for (int nf = 0; nf < 4; ++nf) {
            const int d = w * 64 + nf * 16 + c;
            const float gv = gamma[d], bv = beta[d];
            #pragma unroll
            for (int i = 0; i < 4; ++i) {
                const int r = g * 4 + i;
                out[(size_t)(tok0 + r) * DIM + d] = (acc[nf][i] - mu[i]) * rs[i] * gv + bv;
            }
        }
    }
    __syncthreads();                           // isolate reps

    } // rep loop
}

extern "C" void kernel_launch(void* const* d_in, const int* in_sizes, int n_in,
                              void* d_out, int out_size, void* d_ws, size_t ws_size,
                              hipStream_t stream) {
    const int*   smap  = (const int*)d_in[0];
    const float* table = (const float*)d_in[1];
    const float* gamma = (const float*)d_in[2];
    const float* beta  = (const float*)d_in[3];
    float*       out   = (float*)d_out;

    const int batches = in_sizes[0] / (IMG * IMG);       // = 2
    const int tokens  = batches * HPW * HPW;             // 2048
    const int nblk    = tokens / TPB;                    // 128

    ushort*   Tt2   = (ushort*)d_ws;                     // 512 KB packed table
    unsigned* flags = (unsigned*)(Tt2 + (size_t)64 * 4096);

    fused_one<<<nblk, NT, 0, stream>>>(smap, table, gamma, beta, out, Tt2, flags);
}

// Round 19
// 23.251 us; speedup vs baseline: 2.9456x; 2.9456x over previous
//
#include <hip/hip_runtime.h>

#define IMG   512
#define NCLS  256
#define DIM   1024
#define HPW   32

typedef short bf16x8 __attribute__((ext_vector_type(8)));
typedef float f32x4  __attribute__((ext_vector_type(4)));

__device__ inline ushort bf16rne(float v) {
    unsigned u = __float_as_uint(v);
    return (ushort)((u + 0x7fffu + ((u >> 16) & 1u)) >> 16);
}

// ---------- K1: prep (64 pack + 64 hist blocks, 256 thr) — verbatim R17 ----------
// pack:  Tt2[dtile*4096 + ks*512 + g*128 + c*8 + j] = bf16(table[ks*32+g*8+j][dtile*16+c])
// hist:  Ab[grp][32][256] = bf16(count/256) for one patch-row (32 tokens)
__global__ __launch_bounds__(256)
void prep(const int* __restrict__ smap, const float* __restrict__ table,
          ushort* __restrict__ Tt2, ushort* __restrict__ Ab)
{
    __shared__ ushort   tile[16][264];
    __shared__ unsigned cnt[32 * NCLS];       // 32 KB
    const int t   = threadIdx.x;
    const int bid = blockIdx.x;

    if (bid < 64) {
        const int dtile = bid;
        const float* src = table + (size_t)t * DIM + dtile * 16;
        #pragma unroll
        for (int q = 0; q < 4; ++q) {
            const float4 v = *reinterpret_cast<const float4*>(src + q * 4);
            tile[q * 4 + 0][t] = bf16rne(v.x);
            tile[q * 4 + 1][t] = bf16rne(v.y);
            tile[q * 4 + 2][t] = bf16rne(v.z);
            tile[q * 4 + 3][t] = bf16rne(v.w);
        }
        __syncthreads();
        const int ks   = t >> 5;
        const int g    = (t >> 3) & 3;
        const int c0   = (t & 7) * 2;
        const int cls0 = ks * 32 + g * 8;
        uint4* dst = reinterpret_cast<uint4*>(Tt2 + (size_t)dtile * 4096 + (size_t)t * 16);
        dst[0] = *reinterpret_cast<const uint4*>(&tile[c0][cls0]);
        dst[1] = *reinterpret_cast<const uint4*>(&tile[c0 + 1][cls0]);
    } else {
        const int grp  = bid - 64;
        const int tok0 = grp * 32;
        const int b    = tok0 >> 10;
        const int ph   = (tok0 >> 5) & 31;

        #pragma unroll
        for (int i = t; i < 32 * NCLS; i += 256) cnt[i] = 0u;
        __syncthreads();

        const int row  = t >> 4;              // 0..15
        const int col0 = (t & 15) * 32;       // 0..480
        const int* bp = smap + ((size_t)b * IMG + (size_t)(ph * 16 + row)) * IMG + col0;
        #pragma unroll
        for (int q4 = 0; q4 < 8; ++q4) {
            const int4 q = *reinterpret_cast<const int4*>(bp + q4 * 4);
            unsigned* hp = &cnt[((col0 + q4 * 4) >> 4) * NCLS];
            atomicAdd(&hp[min(max(q.x, 0), NCLS - 1)], 1u);
            atomicAdd(&hp[min(max(q.y, 0), NCLS - 1)], 1u);
            atomicAdd(&hp[min(max(q.z, 0), NCLS - 1)], 1u);
            atomicAdd(&hp[min(max(q.w, 0), NCLS - 1)], 1u);
        }
        __syncthreads();

        ushort* ab = Ab + (size_t)grp * 8192;
        #pragma unroll
        for (int i = t; i < 8192; i += 256)
            ab[i] = (ushort)(__float_as_uint((float)cnt[i] * (1.f / 256.f)) >> 16);
    }
}

// ---------- K2: 256 blocks = (64 grp) x (4 dim-quarters); 32 tok x 256 dims ----------
// Writes pre-LN values (f32) + per-quarter LN partials; NO cross-block sync.
__global__ __launch_bounds__(1024)
void gemm_part(const ushort* __restrict__ Ab, const ushort* __restrict__ Tt2,
               float* __restrict__ preLN, float* __restrict__ pstats)
{
    __shared__ ushort cntb[32][264];          // A: 32 tokens x 256 cls (padded)
    __shared__ float  red[16][2][4][4][2];    // [wave][mf][g][i][{s,s2}]

    const int t    = threadIdx.x;
    const int lane = t & 63;
    const int w    = t >> 6;                  // 16 waves; wave owns 16 dims of the slice
    const int c    = lane & 15;
    const int g    = lane >> 4;

    const int bid  = blockIdx.x;
    const int grp  = bid >> 2;
    const int dq   = bid & 3;                 // dim quarter == sincos quadrant
    const int tok0 = grp * 32;
    const int ph   = (tok0 >> 5) & 31;

    // ---- load fragment-ready A (32x256 bf16 = 16 KB) in one coalesced pass ----
    {
        const uint4 v = reinterpret_cast<const uint4*>(Ab + (size_t)grp * 8192)[t];
        const int idx = t * 8;
        *reinterpret_cast<uint4*>(&cntb[idx >> 8][idx & 255]) = v;
    }
    __syncthreads();

    // ---- MFMA: all 8 B-fragments issued up front (128 KB/block total) ----
    f32x4 acc0 = (f32x4){0.f, 0.f, 0.f, 0.f};
    f32x4 acc1 = (f32x4){0.f, 0.f, 0.f, 0.f};
    const ushort* bt = Tt2 + (size_t)(dq * 16 + w) * 4096 + (size_t)lane * 8;
    bf16x8 bfv[8];
    #pragma unroll
    for (int ks = 0; ks < 8; ++ks)
        bfv[ks] = *reinterpret_cast<const bf16x8*>(bt + ks * 512);
    #pragma unroll
    for (int ks = 0; ks < 8; ++ks) {
        const bf16x8 a0 = *reinterpret_cast<const bf16x8*>(&cntb[c][ks * 32 + g * 8]);
        const bf16x8 a1 = *reinterpret_cast<const bf16x8*>(&cntb[16 + c][ks * 32 + g * 8]);
        acc0 = __builtin_amdgcn_mfma_f32_16x16x32_bf16(a0, bfv[ks], acc0, 0, 0, 0);
        acc1 = __builtin_amdgcn_mfma_f32_16x16x32_bf16(a1, bfv[ks], acc1, 0, 0, 0);
    }

    // ---- pos-embed (verbatim R17).  dim d = dq*256 + w*16 + c; token = mf*16+g*4+i ----
    {
        const float omega = exp2f((float)(w * 16 + c) * (-13.287712379549449f / 256.f));
        if (dq < 2) {
            float sv, cv; __sincosf((float)ph * omega, &sv, &cv);
            const float v = (dq & 1) ? cv : sv;
            #pragma unroll
            for (int i = 0; i < 4; ++i) { acc0[i] += v; acc1[i] += v; }
        } else {
            #pragma unroll
            for (int i = 0; i < 4; ++i) {
                float sv, cv;
                __sincosf((float)(g * 4 + i) * omega, &sv, &cv);
                acc0[i] += (dq & 1) ? cv : sv;
                __sincosf((float)(16 + g * 4 + i) * omega, &sv, &cv);
                acc1[i] += (dq & 1) ? cv : sv;
            }
        }
    }

    // ---- LN partials over this block's 256 dims (verbatim R17) ----
    float ls0[4], ls20[4], ls1[4], ls21[4];
    #pragma unroll
    for (int i = 0; i < 4; ++i) {
        ls0[i] = acc0[i]; ls20[i] = acc0[i] * acc0[i];
        ls1[i] = acc1[i]; ls21[i] = acc1[i] * acc1[i];
    }
    #pragma unroll
    for (int off = 1; off < 16; off <<= 1) {
        #pragma unroll
        for (int i = 0; i < 4; ++i) {
            ls0[i]  += __shfl_xor(ls0[i],  off, 64);
            ls20[i] += __shfl_xor(ls20[i], off, 64);
            ls1[i]  += __shfl_xor(ls1[i],  off, 64);
            ls21[i] += __shfl_xor(ls21[i], off, 64);
        }
    }
    if (c == 0) {
        #pragma unroll
        for (int i = 0; i < 4; ++i) {
            red[w][0][g][i][0] = ls0[i]; red[w][0][g][i][1] = ls20[i];
            red[w][1][g][i][0] = ls1[i]; red[w][1][g][i][1] = ls21[i];
        }
    }
    __syncthreads();

    // ---- plain stores: partial stats + pre-LN values (kernel-boundary coherence) ----
    if (t < 64) {
        const int token = t >> 1, which = t & 1;
        const int mf = token >> 4, gg = (token >> 2) & 3, ii = token & 3;
        float S = 0.f;
        #pragma unroll
        for (int ww = 0; ww < 16; ++ww) S += red[ww][mf][gg][ii][which];
        pstats[(size_t)bid * 64 + token * 2 + which] = S;
    }
    {
        const int ds = w * 16 + c;            // dim within slice
        #pragma unroll
        for (int i = 0; i < 4; ++i) {
            const int r0 = g * 4 + i;
            preLN[((size_t)bid * 32 + r0) * 256 + ds]        = acc0[i];
            preLN[((size_t)bid * 32 + 16 + r0) * 256 + ds]   = acc1[i];
        }
    }
}

// ---------- K3: LN finalize; 256 blocks x 8 tokens; fully coalesced float4 I/O ----------
__global__ __launch_bounds__(1024)
void ln_final(const float* __restrict__ preLN, const float* __restrict__ pstats,
              const float* __restrict__ gamma, const float* __restrict__ beta,
              float* __restrict__ out)
{
    __shared__ float mu_s[8], rs_s[8];
    const int t    = threadIdx.x;
    const int tok0 = blockIdx.x * 8;
    const int grp  = tok0 >> 5;
    const int rb   = tok0 & 31;

    if (t < 8) {
        float S = 0.f, S2 = 0.f;
        #pragma unroll
        for (int dq = 0; dq < 4; ++dq) {
            const size_t base = ((size_t)(grp * 4 + dq) * 32 + rb + t) * 2;
            S  += pstats[base + 0];
            S2 += pstats[base + 1];
        }
        const float mu = S * (1.f / DIM);
        mu_s[t] = mu;
        rs_s[t] = rsqrtf(S2 * (1.f / DIM) - mu * mu + 1e-5f);
    }
    __syncthreads();

    #pragma unroll
    for (int it = 0; it < 2; ++it) {
        const int idx = it * 1024 + t;        // 0..2047 float4s (8 tok x 256 f4)
        const int tk  = idx >> 8;             // token within block
        const int f4  = idx & 255;
        const int d0  = f4 * 4;
        const int dq  = d0 >> 8;
        const int ds  = d0 & 255;
        const float4 v  = *reinterpret_cast<const float4*>(
            preLN + ((size_t)(grp * 4 + dq) * 32 + rb + tk) * 256 + ds);
        const float4 gv = *reinterpret_cast<const float4*>(gamma + d0);
        const float4 bv = *reinterpret_cast<const float4*>(beta + d0);
        const float mu = mu_s[tk], rs = rs_s[tk];
        float4 o;
        o.x = (v.x - mu) * rs * gv.x + bv.x;
        o.y = (v.y - mu) * rs * gv.y + bv.y;
        o.z = (v.z - mu) * rs * gv.z + bv.z;
        o.w = (v.w - mu) * rs * gv.w + bv.w;
        *reinterpret_cast<float4*>(out + (size_t)(tok0 + tk) * DIM + d0) = o;
    }
}

extern "C" void kernel_launch(void* const* d_in, const int* in_sizes, int n_in,
                              void* d_out, int out_size, void* d_ws, size_t ws_size,
                              hipStream_t stream) {
    const int*   smap  = (const int*)d_in[0];
    const float* table = (const float*)d_in[1];
    const float* gamma = (const float*)d_in[2];
    const float* beta  = (const float*)d_in[3];
    float*       out   = (float*)d_out;

    const int batches = in_sizes[0] / (IMG * IMG);       // = 2
    const int tokens  = batches * HPW * HPW;             // 2048
    const int ngrp    = tokens / 32;                     // 64

    ushort* Tt2    = (ushort*)d_ws;                                // 512 KB
    ushort* Ab     = Tt2 + (size_t)64 * 4096;                      // 1 MB
    float*  preLN  = (float*)(Ab + (size_t)ngrp * 8192);           // 8 MB
    float*  pstats = preLN + (size_t)tokens * DIM;                 // 64 KB

    prep<<<64 + ngrp, 256, 0, stream>>>(smap, table, Tt2, Ab);
    gemm_part<<<ngrp * 4, 1024, 0, stream>>>(Ab, Tt2, preLN, pstats);
    ln_final<<<tokens / 8, 1024, 0, stream>>>(preLN, pstats, gamma, beta, out);
}

// Round 20
// 20.476 us; speedup vs baseline: 3.3447x; 1.1355x over previous
//
#include <hip/hip_runtime.h>

#define IMG   512
#define NCLS  256
#define DIM   1024
#define HPW   32
#define TPB   16           // tokens per block = full MFMA M
#define NT    1024         // 16 waves; wave owns 64 dims
#define MAGIC 0x5EEDC0DEu

typedef short bf16x8 __attribute__((ext_vector_type(8)));
typedef float f32x4  __attribute__((ext_vector_type(4)));

__device__ inline ushort bf16rne(float v) {
    unsigned u = __float_as_uint(v);
    return (ushort)((u + 0x7fffu + ((u >> 16) & 1u)) >> 16);
}

// Single launch, 128 blocks x 1024 thr (R16 skeleton + measured fixes):
//  - waves 0-7: pack 1/128 of fragment-ordered Tt2; waves 8-15: zero + histogram
//  - relaxed spin + single acquire (one cache-inv per block, before any Tt2 read)
//  - LDS-staged, fully-coalesced float4 output (kills 2x write amplification)
//   Tt2[dtile*4096 + ks*512 + g*128 + c*8 + j] = bf16(table[ks*32+g*8+j][dtile*16+c])
__global__ __launch_bounds__(NT)
void fused_one(const int* __restrict__ smap, const float* __restrict__ table,
               const float* __restrict__ gamma, const float* __restrict__ beta,
               float* __restrict__ out, ushort* __restrict__ Tt2,
               unsigned* __restrict__ flags)
{
    __shared__ unsigned cnt[TPB * NCLS];      // 16 KB
    __shared__ ushort   pk[2048];             // 4 KB pack staging
    __shared__ ushort   cntb[16][264];        // stride 528 B -> conflict-free b128
    __shared__ float    red[16][4][4][2];     // [wave][g][i][{s,s2}]
    __shared__ float    preOut[16][1028];     // 65.8 KB padded output staging

    const int t    = threadIdx.x;
    const int lane = t & 63;
    const int w    = t >> 6;
    const int c    = lane & 15;
    const int g    = lane >> 4;

    const int bid  = blockIdx.x;
    const int tok0 = bid * TPB;
    const int b    = tok0 >> 10;
    const int ph   = (tok0 >> 5) & 31;
    const int pw0  = tok0 & 31;               // 0 or 16

    const int dtile = bid >> 1;
    const int kh    = bid & 1;

    // ---- 1) wave-split front A: packers load+scatter; others zero hist ----
    if (t < 512) {
        const int cls  = kh * 128 + (t >> 2);
        const int quad = t & 3;
        const float4 v = *reinterpret_cast<const float4*>(
            table + (size_t)cls * DIM + dtile * 16 + quad * 4);
        const int ks = cls >> 5, gg = (cls >> 3) & 3, j = cls & 7;
        ushort* dst = pk + (ks & 3) * 512 + gg * 128 + j;
        dst[(quad * 4 + 0) * 8] = bf16rne(v.x);
        dst[(quad * 4 + 1) * 8] = bf16rne(v.y);
        dst[(quad * 4 + 2) * 8] = bf16rne(v.z);
        dst[(quad * 4 + 3) * 8] = bf16rne(v.w);
    } else {
        #pragma unroll
        for (int i = t - 512; i < TPB * NCLS; i += 512) cnt[i] = 0u;
    }
    __syncthreads();

    // ---- 2) wave-split front B: packers copy-out (system scope); others hist ----
    if (t < 512) {
        #pragma unroll
        for (int k = 0; k < 2; ++k) {
            const int tt = t + k * 512;
            const unsigned val = (unsigned)pk[tt * 2] | ((unsigned)pk[tt * 2 + 1] << 16);
            __hip_atomic_store((unsigned*)Tt2 + (size_t)dtile * 2048 + kh * 1024 + tt, val,
                               __ATOMIC_RELAXED, __HIP_MEMORY_SCOPE_SYSTEM);
        }
    } else {
        const int tt  = t - 512;
        const int row = tt >> 5;              // 0..15
        const int col = (tt & 31) * 8;        // 0..248 (8 px within one patch)
        const int* bp = smap + ((size_t)b * IMG + (size_t)(ph * 16 + row)) * IMG
                             + pw0 * 16 + col;
        const int4 q0 = *reinterpret_cast<const int4*>(bp);
        const int4 q1 = *reinterpret_cast<const int4*>(bp + 4);
        unsigned* hp = &cnt[(col >> 4) * NCLS];
        atomicAdd(&hp[min(max(q0.x, 0), NCLS - 1)], 1u);
        atomicAdd(&hp[min(max(q0.y, 0), NCLS - 1)], 1u);
        atomicAdd(&hp[min(max(q0.z, 0), NCLS - 1)], 1u);
        atomicAdd(&hp[min(max(q0.w, 0), NCLS - 1)], 1u);
        atomicAdd(&hp[min(max(q1.x, 0), NCLS - 1)], 1u);
        atomicAdd(&hp[min(max(q1.y, 0), NCLS - 1)], 1u);
        atomicAdd(&hp[min(max(q1.z, 0), NCLS - 1)], 1u);
        atomicAdd(&hp[min(max(q1.w, 0), NCLS - 1)], 1u);
    }
    __syncthreads();                          // all Tt2 stores + hist complete

    // ---- 3) publish pack completion (release, system) ----
    if (t == 0)
        __hip_atomic_store(&flags[bid], MAGIC, __ATOMIC_RELEASE, __HIP_MEMORY_SCOPE_SYSTEM);

    // ---- 4) counts -> bf16(count/256), exact ----
    for (int i = t; i < TPB * NCLS; i += NT)
        cntb[i >> 8][i & 255] = (ushort)(__float_as_uint((float)cnt[i] * (1.f / 256.f)) >> 16);

    // ---- 5) relaxed spin (no cache-inv per poll), then single acquire ----
    if (t < 128) {
        while (__hip_atomic_load(&flags[t], __ATOMIC_RELAXED,
                                 __HIP_MEMORY_SCOPE_SYSTEM) != MAGIC) {}
    }
    __syncthreads();
    if (t == 0) {
        unsigned x = __hip_atomic_load(&flags[0], __ATOMIC_ACQUIRE,
                                       __HIP_MEMORY_SCOPE_SYSTEM);
        asm volatile("" :: "v"(x));           // keep the acquire load live
    }
    __syncthreads();

    // ---- 6) MFMA K-loop (verbatim R16) ----
    f32x4 acc[4];
    #pragma unroll
    for (int i = 0; i < 4; ++i) acc[i] = (f32x4){0.f, 0.f, 0.f, 0.f};

    const ushort* bt = Tt2 + (size_t)(w * 4) * 4096 + (size_t)lane * 8;
    #pragma unroll 2
    for (int ks = 0; ks < 8; ++ks) {
        const bf16x8 a = *reinterpret_cast<const bf16x8*>(&cntb[c][ks * 32 + g * 8]);
        bf16x8 bfv[4];
        #pragma unroll
        for (int nf = 0; nf < 4; ++nf)
            bfv[nf] = *reinterpret_cast<const bf16x8*>(bt + (size_t)nf * 4096 + ks * 512);
        #pragma unroll
        for (int nf = 0; nf < 4; ++nf)
            acc[nf] = __builtin_amdgcn_mfma_f32_16x16x32_bf16(a, bfv[nf], acc[nf], 0, 0, 0);
    }

    // ---- 7) pos-embed + LN partials (verbatim R16) ----
    const int quad   = w >> 2;
    const int cosSel = quad & 1;
    float ls[4]  = {0, 0, 0, 0};
    float ls2[4] = {0, 0, 0, 0};

    #pragma unroll
    for (int nf = 0; nf < 4; ++nf) {
        const int dlow = (w & 3) * 64 + nf * 16 + c;
        const float omega = exp2f((float)dlow * (-13.287712379549449f / 256.f));
        if (quad < 2) {
            float sv, cv; __sincosf((float)ph * omega, &sv, &cv);
            const float v = cosSel ? cv : sv;
            #pragma unroll
            for (int i = 0; i < 4; ++i) acc[nf][i] += v;
        } else {
            #pragma unroll
            for (int i = 0; i < 4; ++i) {
                float sv, cv; __sincosf((float)(pw0 + g * 4 + i) * omega, &sv, &cv);
                acc[nf][i] += cosSel ? cv : sv;
            }
        }
        #pragma unroll
        for (int i = 0; i < 4; ++i) { ls[i] += acc[nf][i]; ls2[i] += acc[nf][i] * acc[nf][i]; }
    }

    #pragma unroll
    for (int off = 1; off < 16; off <<= 1) {
        #pragma unroll
        for (int i = 0; i < 4; ++i) {
            ls[i]  += __shfl_xor(ls[i],  off, 64);
            ls2[i] += __shfl_xor(ls2[i], off, 64);
        }
    }
    if (c == 0) {
        #pragma unroll
        for (int i = 0; i < 4; ++i) { red[w][g][i][0] = ls[i]; red[w][g][i][1] = ls2[i]; }
    }
    __syncthreads();

    // ---- 8) finalize LN into padded LDS staging (values bit-identical to R16) ----
    {
        float mu[4], rs[4];
        #pragma unroll
        for (int i = 0; i < 4; ++i) {
            float S = 0.f, S2 = 0.f;
            #pragma unroll
            for (int ww = 0; ww < 16; ++ww) { S += red[ww][g][i][0]; S2 += red[ww][g][i][1]; }
            mu[i] = S * (1.f / DIM);
            rs[i] = rsqrtf(S2 * (1.f / DIM) - mu[i] * mu[i] + 1e-5f);
        }
        #pragma unroll
        for (int nf = 0; nf < 4; ++nf) {
            const int d = w * 64 + nf * 16 + c;
            const float gv = gamma[d], bv = beta[d];
            #pragma unroll
            for (int i = 0; i < 4; ++i) {
                const int r = g * 4 + i;
                preOut[r][d] = (acc[nf][i] - mu[i]) * rs[i] * gv + bv;
            }
        }
    }
    __syncthreads();

    // ---- 9) coalesced float4 output copy (full 128 B lines, no RFO) ----
    #pragma unroll
    for (int it = 0; it < 4; ++it) {
        const int idx = it * 1024 + t;        // 0..4095 float4s
        const int row = idx >> 8;             // 0..15
        const int c4  = idx & 255;            // 0..255
        const float4 v = *reinterpret_cast<const float4*>(&preOut[row][c4 * 4]);
        *reinterpret_cast<float4*>(out + (size_t)(tok0 + row) * DIM + c4 * 4) = v;
    }
}

extern "C" void kernel_launch(void* const* d_in, const int* in_sizes, int n_in,
                              void* d_out, int out_size, void* d_ws, size_t ws_size,
                              hipStream_t stream) {
    const int*   smap  = (const int*)d_in[0];
    const float* table = (const float*)d_in[1];
    const float* gamma = (const float*)d_in[2];
    const float* beta  = (const float*)d_in[3];
    float*       out   = (float*)d_out;

    const int batches = in_sizes[0] / (IMG * IMG);       // = 2
    const int tokens  = batches * HPW * HPW;             // 2048
    const int nblk    = tokens / TPB;                    // 128

    ushort*   Tt2   = (ushort*)d_ws;                     // 512 KB packed table
    unsigned* flags = (unsigned*)(Tt2 + (size_t)64 * 4096);

    fused_one<<<nblk, NT, 0, stream>>>(smap, table, gamma, beta, out, Tt2, flags);
}

// Round 21
// 20.378 us; speedup vs baseline: 3.3608x; 1.0048x over previous
//
#include <hip/hip_runtime.h>

#define IMG   512
#define NCLS  256
#define DIM   1024
#define HPW   32
#define TPB   16           // tokens per block = full MFMA M
#define NT    1024         // 16 waves; wave owns 64 dims
#define MAGIC 0x5EEDC0DEu

typedef short bf16x8 __attribute__((ext_vector_type(8)));
typedef float f32x4  __attribute__((ext_vector_type(4)));

__device__ inline ushort bf16rne(float v) {
    unsigned u = __float_as_uint(v);
    return (ushort)((u + 0x7fffu + ((u >> 16) & 1u)) >> 16);
}

// R16 skeleton (best: 19.2 us), single change: software-pipelined MFMA K-loop.
//   Tt2[dtile*4096 + ks*512 + g*128 + c*8 + j] = bf16(table[ks*32+g*8+j][dtile*16+c])
__global__ __launch_bounds__(NT)
void fused_one(const int* __restrict__ smap, const float* __restrict__ table,
               const float* __restrict__ gamma, const float* __restrict__ beta,
               float* __restrict__ out, ushort* __restrict__ Tt2,
               unsigned* __restrict__ flags)
{
    __shared__ unsigned cnt[TPB * NCLS];      // 16 KB
    __shared__ ushort   pk[2048];             // 4 KB pack staging
    __shared__ ushort   cntb[16][264];        // stride 528 B -> conflict-free b128
    __shared__ float    red[16][4][4][2];     // [wave][g][i][{s,s2}]

    const int t    = threadIdx.x;
    const int lane = t & 63;
    const int w    = t >> 6;
    const int c    = lane & 15;
    const int g    = lane >> 4;

    const int bid  = blockIdx.x;
    const int tok0 = bid * TPB;
    const int b    = tok0 >> 10;
    const int ph   = (tok0 >> 5) & 31;
    const int pw0  = tok0 & 31;               // 0 or 16

    const int dtile = bid >> 1;
    const int kh    = bid & 1;

    // ---- 1) pack-load: 128 cls x 16 dims -> LDS scatter (fragment order) ----
    if (t < 512) {
        const int cls  = kh * 128 + (t >> 2);
        const int quad = t & 3;
        const float4 v = *reinterpret_cast<const float4*>(
            table + (size_t)cls * DIM + dtile * 16 + quad * 4);
        const int ks = cls >> 5, gg = (cls >> 3) & 3, j = cls & 7;
        ushort* dst = pk + (ks & 3) * 512 + gg * 128 + j;
        dst[(quad * 4 + 0) * 8] = bf16rne(v.x);
        dst[(quad * 4 + 1) * 8] = bf16rne(v.y);
        dst[(quad * 4 + 2) * 8] = bf16rne(v.z);
        dst[(quad * 4 + 3) * 8] = bf16rne(v.w);
    }
    // ---- 2) zero hist ----
    for (int i = t; i < TPB * NCLS; i += NT) cnt[i] = 0u;
    __syncthreads();

    // ---- 3) pack copy-out: system-scope atomic dwords (bypass L2 -> coherent) ----
    {
        const unsigned val = (unsigned)pk[t * 2] | ((unsigned)pk[t * 2 + 1] << 16);
        __hip_atomic_store((unsigned*)Tt2 + (size_t)dtile * 2048 + kh * 1024 + t, val,
                           __ATOMIC_RELAXED, __HIP_MEMORY_SCOPE_SYSTEM);
    }
    __syncthreads();                          // drains every wave's stores (vmcnt 0)

    // ---- 4) publish pack completion (system-scope release) ----
    if (t == 0)
        __hip_atomic_store(&flags[bid], MAGIC, __ATOMIC_RELEASE, __HIP_MEMORY_SCOPE_SYSTEM);

    // ---- 5) histogram: 16 rows x 256 cols (16 patches), int4 per thread ----
    {
        const int row = t >> 6;               // 0..15
        const int col = (t & 63) * 4;         // 0..252
        const int4 q = *reinterpret_cast<const int4*>(
            smap + ((size_t)b * IMG + (size_t)(ph * 16 + row)) * IMG + pw0 * 16 + col);
        unsigned* hp = &cnt[(col >> 4) * NCLS];
        atomicAdd(&hp[min(max(q.x, 0), NCLS - 1)], 1u);
        atomicAdd(&hp[min(max(q.y, 0), NCLS - 1)], 1u);
        atomicAdd(&hp[min(max(q.z, 0), NCLS - 1)], 1u);
        atomicAdd(&hp[min(max(q.w, 0), NCLS - 1)], 1u);
    }
    __syncthreads();

    // ---- 6) counts -> bf16(count/256), exact ----
    for (int i = t; i < TPB * NCLS; i += NT)
        cntb[i >> 8][i & 255] = (ushort)(__float_as_uint((float)cnt[i] * (1.f / 256.f)) >> 16);

    // ---- 7) wait for all packers (system-scope acquire) ----
    if (t < 128) {
        while (__hip_atomic_load(&flags[t], __ATOMIC_ACQUIRE,
                                 __HIP_MEMORY_SCOPE_SYSTEM) != MAGIC) {}
    }
    __syncthreads();

    // ---- 8) MFMA K-loop, software-pipelined: per-nf tiles, B double-buffered ----
    // Wave's B region is contiguous 16 KB; prefetch tile nf+1's 8 fragments while
    // running tile nf's 8 chained MFMAs -> one latency exposure instead of four.
    f32x4 acc[4];
    const ushort* bt = Tt2 + (size_t)(w * 4) * 4096 + (size_t)lane * 8;

    bf16x8 bP[8], bQ[8];
    #pragma unroll
    for (int ks = 0; ks < 8; ++ks)
        bP[ks] = *reinterpret_cast<const bf16x8*>(bt + ks * 512);

    #pragma unroll
    for (int nf = 0; nf < 4; ++nf) {
        acc[nf] = (f32x4){0.f, 0.f, 0.f, 0.f};
        if (nf & 1) {                         // current tile in bQ, prefetch into bP
            if (nf < 3) {
                #pragma unroll
                for (int ks = 0; ks < 8; ++ks)
                    bP[ks] = *reinterpret_cast<const bf16x8*>(
                        bt + (size_t)(nf + 1) * 4096 + ks * 512);
            }
            #pragma unroll
            for (int ks = 0; ks < 8; ++ks) {
                const bf16x8 a = *reinterpret_cast<const bf16x8*>(&cntb[c][ks * 32 + g * 8]);
                acc[nf] = __builtin_amdgcn_mfma_f32_16x16x32_bf16(a, bQ[ks], acc[nf], 0, 0, 0);
            }
        } else {                              // current tile in bP, prefetch into bQ
            if (nf < 3) {
                #pragma unroll
                for (int ks = 0; ks < 8; ++ks)
                    bQ[ks] = *reinterpret_cast<const bf16x8*>(
                        bt + (size_t)(nf + 1) * 4096 + ks * 512);
            }
            #pragma unroll
            for (int ks = 0; ks < 8; ++ks) {
                const bf16x8 a = *reinterpret_cast<const bf16x8*>(&cntb[c][ks * 32 + g * 8]);
                acc[nf] = __builtin_amdgcn_mfma_f32_16x16x32_bf16(a, bP[ks], acc[nf], 0, 0, 0);
            }
        }
    }

    // ---- 9) pos-embed + LN partials (verbatim R16) ----
    const int quad   = w >> 2;
    const int cosSel = quad & 1;
    float ls[4]  = {0, 0, 0, 0};
    float ls2[4] = {0, 0, 0, 0};

    #pragma unroll
    for (int nf = 0; nf < 4; ++nf) {
        const int dlow = (w & 3) * 64 + nf * 16 + c;
        const float omega = exp2f((float)dlow * (-13.287712379549449f / 256.f));
        if (quad < 2) {
            float sv, cv; __sincosf((float)ph * omega, &sv, &cv);
            const float v = cosSel ? cv : sv;
            #pragma unroll
            for (int i = 0; i < 4; ++i) acc[nf][i] += v;
        } else {
            #pragma unroll
            for (int i = 0; i < 4; ++i) {
                float sv, cv; __sincosf((float)(pw0 + g * 4 + i) * omega, &sv, &cv);
                acc[nf][i] += cosSel ? cv : sv;
            }
        }
        #pragma unroll
        for (int i = 0; i < 4; ++i) { ls[i] += acc[nf][i]; ls2[i] += acc[nf][i] * acc[nf][i]; }
    }

    #pragma unroll
    for (int off = 1; off < 16; off <<= 1) {
        #pragma unroll
        for (int i = 0; i < 4; ++i) {
            ls[i]  += __shfl_xor(ls[i],  off, 64);
            ls2[i] += __shfl_xor(ls2[i], off, 64);
        }
    }
    if (c == 0) {
        #pragma unroll
        for (int i = 0; i < 4; ++i) { red[w][g][i][0] = ls[i]; red[w][g][i][1] = ls2[i]; }
    }
    __syncthreads();

    // ---- 10) finalize LN + store (verbatim R16) ----
    {
        float mu[4], rs[4];
        #pragma unroll
        for (int i = 0; i < 4; ++i) {
            float S = 0.f, S2 = 0.f;
            #pragma unroll
            for (int ww = 0; ww < 16; ++ww) { S += red[ww][g][i][0]; S2 += red[ww][g][i][1]; }
            mu[i] = S * (1.f / DIM);
            rs[i] = rsqrtf(S2 * (1.f / DIM) - mu[i] * mu[i] + 1e-5f);
        }
        #pragma unroll
        for (int nf = 0; nf < 4; ++nf) {
            const int d = w * 64 + nf * 16 + c;
            const float gv = gamma[d], bv = beta[d];
            #pragma unroll
            for (int i = 0; i < 4; ++i) {
                const int r = g * 4 + i;
                out[(size_t)(tok0 + r) * DIM + d] = (acc[nf][i] - mu[i]) * rs[i] * gv + bv;
            }
        }
    }
}

extern "C" void kernel_launch(void* const* d_in, const int* in_sizes, int n_in,
                              void* d_out, int out_size, void* d_ws, size_t ws_size,
                              hipStream_t stream) {
    const int*   smap  = (const int*)d_in[0];
    const float* table = (const float*)d_in[1];
    const float* gamma = (const float*)d_in[2];
    const float* beta  = (const float*)d_in[3];
    float*       out   = (float*)d_out;

    const int batches = in_sizes[0] / (IMG * IMG);       // = 2
    const int tokens  = batches * HPW * HPW;             // 2048
    const int nblk    = tokens / TPB;                    // 128

    ushort*   Tt2   = (ushort*)d_ws;                     // 512 KB packed table
    unsigned* flags = (unsigned*)(Tt2 + (size_t)64 * 4096);

    fused_one<<<nblk, NT, 0, stream>>>(smap, table, gamma, beta, out, Tt2, flags);
}